// Round 8
// baseline (324.197 us; speedup 1.0000x reference)
//
#include <hip/hip_runtime.h>
#include <hip/hip_bf16.h>

typedef __hip_bfloat16 bf16;
typedef __attribute__((ext_vector_type(8))) short short8;   // 8 bf16 = 4 VGPRs
typedef __attribute__((ext_vector_type(4))) float f32x4;    // MFMA C/D

#define BB 4
#define NN 2048
#define DD 256
#define HH 8
#define HD 32
#define BN (BB*NN)          // 8192
#define ELEMS (BN*DD)       // 2097152
#define TKT 64              // keys staged per LDS tile (attn)
#define TQB 128             // queries per block (4 waves x 32)
#define TSTR 72             // t_tile row stride (64 + 8 pad): bank-uniform
#define PSTR 44             // p_tile row stride (32 + 12 pad): bank-uniform

// ---------------------------------------------------------------------------
// Scratch in module .bss (~29 MB).
// ---------------------------------------------------------------------------
__device__ int g_isf32;
__device__ __attribute__((aligned(256))) unsigned short g_qb [ELEMS]; // [bh][n][d] bf16
__device__ __attribute__((aligned(256))) unsigned short g_kb [ELEMS]; // [bh][n][d] bf16
__device__ __attribute__((aligned(256))) unsigned short g_tA [ELEMS]; // [bh][d][n] bf16
__device__ __attribute__((aligned(256))) unsigned short g_tB [ELEMS]; // [bh][d][n] bf16
__device__ __attribute__((aligned(256))) float          g_acc[ELEMS]; // [b][n][D] f32
__device__ __attribute__((aligned(256))) unsigned short g_xb [ELEMS]; // x bf16 [bn][d]
__device__ __attribute__((aligned(256))) unsigned short g_wt [4*DD*DD]; // W^T bf16 [mat][n][k]
__device__ __attribute__((aligned(256))) float g_bias[4*DD];
__device__ __attribute__((aligned(256))) float g_cf[HH*4];

__device__ __forceinline__ float b2f(unsigned short u) {
    union { unsigned int i; float f; } c; c.i = ((unsigned int)u) << 16; return c.f;
}
__device__ __forceinline__ unsigned short f2b(float f) {
    bf16 h = __float2bfloat16(f);
    return *reinterpret_cast<unsigned short*>(&h);
}
__device__ __forceinline__ float ldin(const void* p, int i, int f32m) {
    return f32m ? ((const float*)p)[i] : b2f(((const unsigned short*)p)[i]);
}

// ---------------------------------------------------------------------------
// Kernel 0: dtype probe (unchanged — verified rounds 4-7).
// ---------------------------------------------------------------------------
__global__ __launch_bounds__(256) void probe_kernel(const void* __restrict__ x)
{
    __shared__ int cnt;
    if (threadIdx.x == 0) cnt = 0;
    __syncthreads();
    const unsigned short* u = (const unsigned short*)x;
    int w = 0;
    for (int i = threadIdx.x; i < 1024; i += 256) {
        const int e = (u[2 * i] >> 7) & 0xFF;
        if (e < 100 || e > 140) ++w;
    }
    atomicAdd(&cnt, w);
    __syncthreads();
    if (threadIdx.x == 0) g_isf32 = (cnt > 300) ? 1 : 0;
}

// ---------------------------------------------------------------------------
// Prep 1: x -> bf16.
// ---------------------------------------------------------------------------
__global__ __launch_bounds__(256) void prep_x_kernel(const void* __restrict__ x)
{
    const int f32m = g_isf32;
    const size_t i0 = ((size_t)blockIdx.x * 256 + threadIdx.x) * 8;
    union { uint4 v; unsigned short s[8]; } o;
    if (f32m) {
        const float4 a = *(const float4*)((const float*)x + i0);
        const float4 b = *(const float4*)((const float*)x + i0 + 4);
        o.s[0]=f2b(a.x); o.s[1]=f2b(a.y); o.s[2]=f2b(a.z); o.s[3]=f2b(a.w);
        o.s[4]=f2b(b.x); o.s[5]=f2b(b.y); o.s[6]=f2b(b.z); o.s[7]=f2b(b.w);
    } else {
        o.v = *(const uint4*)((const unsigned short*)x + i0);
    }
    *(uint4*)(g_xb + i0) = o.v;
}

// ---------------------------------------------------------------------------
// Prep 2: transpose W[k][n] -> g_wt[mat][n][k] bf16; block(0,0) also preps
// biases + coeffs to f32 (merged prep_small — saves a launch).
// ---------------------------------------------------------------------------
__global__ __launch_bounds__(256) void prep_w_kernel(
    const void* W0, const void* W1, const void* W2, const void* W3,
    const void* bq, const void* bk, const void* bv, const void* bo,
    const void* coeffs)
{
    const int f32m = g_isf32;
    __shared__ unsigned short tile[64][65];
    const int mat = blockIdx.y;
    const void* W = (mat == 0) ? W0 : (mat == 1) ? W1 : (mat == 2) ? W2 : W3;
    const int k0 = (blockIdx.x >> 2) * 64;
    const int n0 = (blockIdx.x & 3) * 64;
    const int t  = threadIdx.x;

    if (blockIdx.x == 0 && blockIdx.y == 0) {
        g_bias[0 * DD + t] = ldin(bq, t, f32m);
        g_bias[1 * DD + t] = ldin(bk, t, f32m);
        g_bias[2 * DD + t] = ldin(bv, t, f32m);
        g_bias[3 * DD + t] = ldin(bo, t, f32m);
        if (t < 32) g_cf[t] = ldin(coeffs, t, f32m);
    }

    #pragma unroll
    for (int it = 0; it < 16; ++it) {
        const int flat = it * 256 + t;
        const int i = flat >> 6, j = flat & 63;
        tile[j][i] = f2b(ldin(W, (k0 + i) * DD + n0 + j, f32m));
    }
    __syncthreads();
    unsigned short* wt = g_wt + mat * DD * DD;
    #pragma unroll
    for (int it = 0; it < 16; ++it) {
        const int flat = it * 256 + t;
        const int nl = flat >> 6, kl = flat & 63;
        wt[(n0 + nl) * DD + k0 + kl] = tile[nl][kl];
    }
}

// ---------------------------------------------------------------------------
// Kernel 1: QKV projection GEMM (unchanged from round 7).
// ---------------------------------------------------------------------------
__global__ __launch_bounds__(256) void qkv_gemm_kernel()
{
    __shared__ unsigned short xs[64 * 32];
    __shared__ unsigned short wl[64 * 32];
    const int t  = threadIdx.x;
    const int w  = t >> 6, l = t & 63, lg = l >> 4, ln = l & 15;
    const int r0 = blockIdx.x * 64;
    const int n0 = blockIdx.y * 64;
    const int mat = blockIdx.z;
    const unsigned short* wt = g_wt + mat * DD * DD;
    const int sr = t >> 2, sc = (t & 3) * 8;

    f32x4 acc[4] = {{0,0,0,0},{0,0,0,0},{0,0,0,0},{0,0,0,0}};

    for (int kc = 0; kc < DD; kc += 32) {
        __syncthreads();
        *(uint4*)(xs + sr * 32 + sc) =
            *(const uint4*)(g_xb + (size_t)(r0 + sr) * DD + kc + sc);
        *(uint4*)(wl + sr * 32 + sc) =
            *(const uint4*)(wt + (size_t)(n0 + sr) * DD + kc + sc);
        __syncthreads();
        const short8 af = *(const short8*)(xs + (w * 16 + ln) * 32 + lg * 8);
        #pragma unroll
        for (int s = 0; s < 4; ++s) {
            const short8 bfr = *(const short8*)(wl + (s * 16 + ln) * 32 + lg * 8);
            acc[s] = __builtin_amdgcn_mfma_f32_16x16x32_bf16(af, bfr, acc[s], 0, 0, 0);
        }
    }

    #pragma unroll
    for (int s = 0; s < 4; ++s) {
        const int j = n0 + s * 16 + ln;
        const float bias = g_bias[mat * DD + j];
        const int h = j >> 5, dd = j & 31;
        #pragma unroll
        for (int r = 0; r < 4; ++r) {
            const int rn = r0 + w * 16 + lg * 4 + r;
            const int b = rn >> 11, n = rn & (NN - 1);
            const int bh = b * HH + h;
            const float val = acc[s][r] + bias;
            if (mat == 0) {
                g_qb[((size_t)bh * NN + n) * HD + dd] = f2b(val);
            } else if (mat == 1) {
                g_kb[((size_t)bh * NN + n) * HD + dd] = f2b(val);
            } else {
                g_tA[((size_t)bh * HD + dd) * NN + n] = f2b(val);
                g_acc[(size_t)rn * DD + j] = g_cf[h * 4] * val;
            }
        }
    }
}

// ---------------------------------------------------------------------------
// Kernel 2 (RESTRUCTURED): attention pass.
// Block = 1 head x 128 queries; wave = 32 queries (2 Q-frags) — k/t fragment
// reads amortized over 2x the MFMAs vs r7.  Bank-conflict fixes:
//  - t_tile row stride 72 u16 (stride 36 words -> uniform 8 accesses/bank;
//    r7's stride-32 layout had ln vanish from the bank index: 2x over min)
//  - p_tile row stride 44 u16 (stride 22 words: b16 scatter writes land on
//    disjoint 8-bank spans per lg; r7 had 4-way lg aliasing, 6M cyc/disp)
//  - k_tile stride 32 kept (16(ln&1)+4lg base is already uniform-minimal)
// P tile is WAVE-PRIVATE -> __threadfence_block() (lgkmcnt drain) replaces
// the per-chunk __syncthreads(): 2 barriers/tile instead of 4.
// ---------------------------------------------------------------------------
__global__ __launch_bounds__(256) void attn_pass_kernel(const int kidx, const int dir)
{
    __shared__ unsigned short k_tile[TKT * HD];       // 4096 B
    __shared__ unsigned short t_tile[HD * TSTR];      // 4608 B
    __shared__ unsigned short p_tile[4 * 2 * 16 * PSTR]; // 11264 B

    const unsigned short* __restrict__ tin  = dir ? g_tB : g_tA;
    unsigned short*       __restrict__ tout = dir ? g_tA : g_tB;

    const int tid = threadIdx.x;
    const int w   = tid >> 6;
    const int l   = tid & 63;
    const int lg  = l >> 4;
    const int ln  = l & 15;

    const int bh = blockIdx.x >> 4;    // b*H + h
    const int qt = blockIdx.x & 15;
    const int h  = bh & (HH - 1);
    const int b  = bh >> 3;
    const int q0 = qt * TQB + w * 32;  // first of this wave's 32 queries

    // 2 Q A-fragments: rows q0..q0+15 and q0+16..q0+31
    short8 qfrag[2];
    #pragma unroll
    for (int qi = 0; qi < 2; ++qi)
        qfrag[qi] = *(const short8*)(g_qb +
            ((size_t)bh * NN + q0 + qi * 16 + ln) * HD + lg * 8);

    const unsigned short* kbase = g_kb + (size_t)bh * NN * HD;
    const unsigned short* tbase = tin  + (size_t)bh * HD * NN;
    unsigned short* pw0 = p_tile + (w * 2 + 0) * 16 * PSTR;
    unsigned short* pw1 = p_tile + (w * 2 + 1) * 16 * PSTR;

    const float scale = 0.17677669529663687f;      // 1/sqrt(32)
    f32x4 oacc[2][2] = {{{0,0,0,0},{0,0,0,0}},{{0,0,0,0},{0,0,0,0}}};
    float lsum[2][4] = {{0,0,0,0},{0,0,0,0}};
    const f32x4 zero = {0.f, 0.f, 0.f, 0.f};

    for (int kt = 0; kt < NN / TKT; ++kt) {
        __syncthreads();
        // ---- stage K (64x32, stride 32) and T (32x64, stride 72)
        {
            const int kr = tid >> 2, kc = (tid & 3) * 8;
            *(uint4*)(k_tile + kr * HD + kc) =
                *(const uint4*)(kbase + (size_t)(kt * TKT + kr) * HD + kc);
            const int tr = tid >> 3, tc = (tid & 7) * 8;
            *(uint4*)(t_tile + tr * TSTR + tc) =
                *(const uint4*)(tbase + (size_t)tr * NN + kt * TKT + tc);
        }
        __syncthreads();

        #pragma unroll
        for (int c = 0; c < 2; ++c) {                  // 32-key chunks
            const short8 kf0 = *(const short8*)(k_tile + (c * 32 + ln) * HD + lg * 8);
            const short8 kf1 = *(const short8*)(k_tile + (c * 32 + 16 + ln) * HD + lg * 8);
            #pragma unroll
            for (int qi = 0; qi < 2; ++qi) {
                f32x4 s0 = __builtin_amdgcn_mfma_f32_16x16x32_bf16(qfrag[qi], kf0, zero, 0, 0, 0);
                f32x4 s1 = __builtin_amdgcn_mfma_f32_16x16x32_bf16(qfrag[qi], kf1, zero, 0, 0, 0);
                unsigned short* pq = qi ? pw1 : pw0;
                #pragma unroll
                for (int r = 0; r < 4; ++r) {
                    const float p0 = __expf(s0[r] * scale);
                    const float p1 = __expf(s1[r] * scale);
                    lsum[qi][r] += p0 + p1;
                    pq[(lg * 4 + r) * PSTR + ln]      = f2b(p0);
                    pq[(lg * 4 + r) * PSTR + ln + 16] = f2b(p1);
                }
            }
            __threadfence_block();   // own-wave LDS drain (P is wave-private)

            const short8 tf0 = *(const short8*)(t_tile + ln * TSTR + c * 32 + lg * 8);
            const short8 tf1 = *(const short8*)(t_tile + (ln + 16) * TSTR + c * 32 + lg * 8);
            #pragma unroll
            for (int qi = 0; qi < 2; ++qi) {
                const unsigned short* pq = qi ? pw1 : pw0;
                const short8 pf = *(const short8*)(pq + ln * PSTR + lg * 8);
                oacc[qi][0] = __builtin_amdgcn_mfma_f32_16x16x32_bf16(pf, tf0, oacc[qi][0], 0, 0, 0);
                oacc[qi][1] = __builtin_amdgcn_mfma_f32_16x16x32_bf16(pf, tf1, oacc[qi][1], 0, 0, 0);
            }
        }
    }

    // ---- softmax denominators: reduce over the 16 col-lanes
    #pragma unroll
    for (int mask = 1; mask <= 8; mask <<= 1)
        #pragma unroll
        for (int qi = 0; qi < 2; ++qi)
            #pragma unroll
            for (int r = 0; r < 4; ++r)
                lsum[qi][r] += __shfl_xor(lsum[qi][r], mask, 64);

    // ---- write t_out (dim-major bf16) + fused g_acc += c_k * t
    const float ck = g_cf[h * 4 + kidx];
    #pragma unroll
    for (int qi = 0; qi < 2; ++qi) {
        #pragma unroll
        for (int m = 0; m < 2; ++m) {
            const int dim = ln + 16 * m;
            const f32x4 oa = oacc[qi][m];
            #pragma unroll
            for (int r = 0; r < 4; ++r) {
                const int qq = q0 + qi * 16 + lg * 4 + r;
                const float val = oa[r] / lsum[qi][r];
                tout[((size_t)bh * HD + dim) * NN + qq] = f2b(val);
                float* ga = g_acc + ((size_t)(b * NN + qq)) * DD + h * HD + dim;
                *ga += ck * val;
            }
        }
    }
}

// ---------------------------------------------------------------------------
// Kernel 3: output projection GEMM (unchanged from round 7).
// ---------------------------------------------------------------------------
__global__ __launch_bounds__(256) void out_gemm_kernel(void* __restrict__ out)
{
    __shared__ unsigned short xs[64 * 32];
    __shared__ unsigned short wl[64 * 32];
    const int f32m = g_isf32;
    const int t  = threadIdx.x;
    const int w  = t >> 6, l = t & 63, lg = l >> 4, ln = l & 15;
    const int r0 = blockIdx.x * 64;
    const int n0 = blockIdx.y * 64;
    const unsigned short* wt = g_wt + 3 * DD * DD;
    const int sr = t >> 2, sc = (t & 3) * 8;

    f32x4 acc[4] = {{0,0,0,0},{0,0,0,0},{0,0,0,0},{0,0,0,0}};

    for (int kc = 0; kc < DD; kc += 32) {
        __syncthreads();
        {
            const float* src = g_acc + (size_t)(r0 + sr) * DD + kc + sc;
            const float4 a = *(const float4*)src;
            const float4 b = *(const float4*)(src + 4);
            union { uint4 v; unsigned short s[8]; } o;
            o.s[0]=f2b(a.x); o.s[1]=f2b(a.y); o.s[2]=f2b(a.z); o.s[3]=f2b(a.w);
            o.s[4]=f2b(b.x); o.s[5]=f2b(b.y); o.s[6]=f2b(b.z); o.s[7]=f2b(b.w);
            *(uint4*)(xs + sr * 32 + sc) = o.v;
        }
        *(uint4*)(wl + sr * 32 + sc) =
            *(const uint4*)(wt + (size_t)(n0 + sr) * DD + kc + sc);
        __syncthreads();
        const short8 af = *(const short8*)(xs + (w * 16 + ln) * 32 + lg * 8);
        #pragma unroll
        for (int s = 0; s < 4; ++s) {
            const short8 bfr = *(const short8*)(wl + (s * 16 + ln) * 32 + lg * 8);
            acc[s] = __builtin_amdgcn_mfma_f32_16x16x32_bf16(af, bfr, acc[s], 0, 0, 0);
        }
    }

    #pragma unroll
    for (int s = 0; s < 4; ++s) {
        const int j = n0 + s * 16 + ln;
        const float bias = g_bias[3 * DD + j];
        #pragma unroll
        for (int r = 0; r < 4; ++r) {
            const int rn = r0 + w * 16 + lg * 4 + r;
            const float val = acc[s][r] + bias;
            if (f32m) ((float*)out)[(size_t)rn * DD + j] = val;
            else      ((bf16*)out)[(size_t)rn * DD + j] = __float2bfloat16(val);
        }
    }
}

// ---------------------------------------------------------------------------
extern "C" void kernel_launch(void* const* d_in, const int* in_sizes, int n_in,
                              void* d_out, int out_size, void* d_ws, size_t ws_size,
                              hipStream_t stream)
{
    const void* x      = d_in[0];
    const void* Wq     = d_in[1];
    const void* bq     = d_in[2];
    const void* Wk     = d_in[3];
    const void* bk     = d_in[4];
    const void* Wv     = d_in[5];
    const void* bv     = d_in[6];
    const void* Wo     = d_in[7];
    const void* bo     = d_in[8];
    const void* coeffs = d_in[9];
    (void)d_ws; (void)ws_size; (void)in_sizes; (void)n_in; (void)out_size;

    probe_kernel<<<1, 256, 0, stream>>>(x);

    prep_x_kernel<<<ELEMS / (256 * 8), 256, 0, stream>>>(x);
    prep_w_kernel<<<dim3(16, 4), 256, 0, stream>>>(Wq, Wk, Wv, Wo,
                                                   bq, bk, bv, bo, coeffs);

    qkv_gemm_kernel<<<dim3(128, 4, 3), 256, 0, stream>>>();

    const int agrid = (BB * HH) * (NN / TQB);   // 32 * 16 = 512 blocks
    attn_pass_kernel<<<agrid, 256, 0, stream>>>(1, 0); // tA -> tB
    attn_pass_kernel<<<agrid, 256, 0, stream>>>(2, 1); // tB -> tA
    attn_pass_kernel<<<agrid, 256, 0, stream>>>(3, 0); // tA -> tB

    out_gemm_kernel<<<dim3(128, 4), 256, 0, stream>>>(d_out);
}

// Round 9
// 276.929 us; speedup vs baseline: 1.1707x; 1.1707x over previous
//
#include <hip/hip_runtime.h>
#include <hip/hip_bf16.h>

typedef __hip_bfloat16 bf16;
typedef __attribute__((ext_vector_type(8))) short short8;   // 8 bf16 = 4 VGPRs
typedef __attribute__((ext_vector_type(4))) float f32x4;    // MFMA C/D

#define BB 4
#define NN 2048
#define DD 256
#define HH 8
#define HD 32
#define BN (BB*NN)          // 8192
#define ELEMS (BN*DD)       // 2097152

// ---------------------------------------------------------------------------
// Scratch in module .bss (~29 MB).
// ---------------------------------------------------------------------------
__device__ int g_isf32;
__device__ __attribute__((aligned(256))) unsigned short g_qb [ELEMS]; // [bh][n][d] bf16 (pre-scaled)
__device__ __attribute__((aligned(256))) unsigned short g_kb [ELEMS]; // [bh][n][d] bf16
__device__ __attribute__((aligned(256))) unsigned short g_tA [ELEMS]; // [bh][d][n] bf16
__device__ __attribute__((aligned(256))) unsigned short g_tB [ELEMS]; // [bh][d][n] bf16
__device__ __attribute__((aligned(256))) float          g_acc[ELEMS]; // [b][n][D] f32
__device__ __attribute__((aligned(256))) unsigned short g_xb [ELEMS]; // x bf16 [bn][d]
__device__ __attribute__((aligned(256))) unsigned short g_wt [4*DD*DD]; // W^T bf16 [mat][n][k]
__device__ __attribute__((aligned(256))) float g_bias[4*DD];
__device__ __attribute__((aligned(256))) float g_cf[HH*4];

__device__ __forceinline__ float b2f(unsigned short u) {
    union { unsigned int i; float f; } c; c.i = ((unsigned int)u) << 16; return c.f;
}
__device__ __forceinline__ unsigned short f2b(float f) {
    bf16 h = __float2bfloat16(f);
    return *reinterpret_cast<unsigned short*>(&h);
}
__device__ __forceinline__ unsigned int pack2(float a, float b) {
    return (unsigned int)f2b(a) | ((unsigned int)f2b(b) << 16);
}
__device__ __forceinline__ float ldin(const void* p, int i, int f32m) {
    return f32m ? ((const float*)p)[i] : b2f(((const unsigned short*)p)[i]);
}

// ---------------------------------------------------------------------------
// Kernel 0: dtype probe (unchanged — verified rounds 4-8).
// ---------------------------------------------------------------------------
__global__ __launch_bounds__(256) void probe_kernel(const void* __restrict__ x)
{
    __shared__ int cnt;
    if (threadIdx.x == 0) cnt = 0;
    __syncthreads();
    const unsigned short* u = (const unsigned short*)x;
    int w = 0;
    for (int i = threadIdx.x; i < 1024; i += 256) {
        const int e = (u[2 * i] >> 7) & 0xFF;
        if (e < 100 || e > 140) ++w;
    }
    atomicAdd(&cnt, w);
    __syncthreads();
    if (threadIdx.x == 0) g_isf32 = (cnt > 300) ? 1 : 0;
}

// ---------------------------------------------------------------------------
// Prep 1: x -> bf16.
// ---------------------------------------------------------------------------
__global__ __launch_bounds__(256) void prep_x_kernel(const void* __restrict__ x)
{
    const int f32m = g_isf32;
    const size_t i0 = ((size_t)blockIdx.x * 256 + threadIdx.x) * 8;
    union { uint4 v; unsigned short s[8]; } o;
    if (f32m) {
        const float4 a = *(const float4*)((const float*)x + i0);
        const float4 b = *(const float4*)((const float*)x + i0 + 4);
        o.s[0]=f2b(a.x); o.s[1]=f2b(a.y); o.s[2]=f2b(a.z); o.s[3]=f2b(a.w);
        o.s[4]=f2b(b.x); o.s[5]=f2b(b.y); o.s[6]=f2b(b.z); o.s[7]=f2b(b.w);
    } else {
        o.v = *(const uint4*)((const unsigned short*)x + i0);
    }
    *(uint4*)(g_xb + i0) = o.v;
}

// ---------------------------------------------------------------------------
// Prep 2: transpose W[k][n] -> g_wt[mat][n][k] bf16; block(0,0) also preps
// biases + coeffs to f32.
// ---------------------------------------------------------------------------
__global__ __launch_bounds__(256) void prep_w_kernel(
    const void* W0, const void* W1, const void* W2, const void* W3,
    const void* bq, const void* bk, const void* bv, const void* bo,
    const void* coeffs)
{
    const int f32m = g_isf32;
    __shared__ unsigned short tile[64][65];
    const int mat = blockIdx.y;
    const void* W = (mat == 0) ? W0 : (mat == 1) ? W1 : (mat == 2) ? W2 : W3;
    const int k0 = (blockIdx.x >> 2) * 64;
    const int n0 = (blockIdx.x & 3) * 64;
    const int t  = threadIdx.x;

    if (blockIdx.x == 0 && blockIdx.y == 0) {
        g_bias[0 * DD + t] = ldin(bq, t, f32m);
        g_bias[1 * DD + t] = ldin(bk, t, f32m);
        g_bias[2 * DD + t] = ldin(bv, t, f32m);
        g_bias[3 * DD + t] = ldin(bo, t, f32m);
        if (t < 32) g_cf[t] = ldin(coeffs, t, f32m);
    }

    #pragma unroll
    for (int it = 0; it < 16; ++it) {
        const int flat = it * 256 + t;
        const int i = flat >> 6, j = flat & 63;
        tile[j][i] = f2b(ldin(W, (k0 + i) * DD + n0 + j, f32m));
    }
    __syncthreads();
    unsigned short* wt = g_wt + mat * DD * DD;
    #pragma unroll
    for (int it = 0; it < 16; ++it) {
        const int flat = it * 256 + t;
        const int nl = flat >> 6, kl = flat & 63;
        wt[(n0 + nl) * DD + k0 + kl] = tile[nl][kl];
    }
}

// ---------------------------------------------------------------------------
// Kernel 1: QKV projection GEMM.  q is PRE-SCALED by 1/sqrt(hd)*log2(e) so
// the attention kernel can use exp2 directly (saves a v_mul per score).
// ---------------------------------------------------------------------------
__global__ __launch_bounds__(256) void qkv_gemm_kernel()
{
    __shared__ unsigned short xs[64 * 32];
    __shared__ unsigned short wl[64 * 32];
    const int t  = threadIdx.x;
    const int w  = t >> 6, l = t & 63, lg = l >> 4, ln = l & 15;
    const int r0 = blockIdx.x * 64;
    const int n0 = blockIdx.y * 64;
    const int mat = blockIdx.z;
    const unsigned short* wt = g_wt + mat * DD * DD;
    const int sr = t >> 2, sc = (t & 3) * 8;

    f32x4 acc[4] = {{0,0,0,0},{0,0,0,0},{0,0,0,0},{0,0,0,0}};

    for (int kc = 0; kc < DD; kc += 32) {
        __syncthreads();
        *(uint4*)(xs + sr * 32 + sc) =
            *(const uint4*)(g_xb + (size_t)(r0 + sr) * DD + kc + sc);
        *(uint4*)(wl + sr * 32 + sc) =
            *(const uint4*)(wt + (size_t)(n0 + sr) * DD + kc + sc);
        __syncthreads();
        const short8 af = *(const short8*)(xs + (w * 16 + ln) * 32 + lg * 8);
        #pragma unroll
        for (int s = 0; s < 4; ++s) {
            const short8 bfr = *(const short8*)(wl + (s * 16 + ln) * 32 + lg * 8);
            acc[s] = __builtin_amdgcn_mfma_f32_16x16x32_bf16(af, bfr, acc[s], 0, 0, 0);
        }
    }

    const float QS = 0.17677669529663687f * 1.4426950408889634f; // scale*log2e
    #pragma unroll
    for (int s = 0; s < 4; ++s) {
        const int j = n0 + s * 16 + ln;
        const float bias = g_bias[mat * DD + j];
        const int h = j >> 5, dd = j & 31;
        #pragma unroll
        for (int r = 0; r < 4; ++r) {
            const int rn = r0 + w * 16 + lg * 4 + r;
            const int b = rn >> 11, n = rn & (NN - 1);
            const int bh = b * HH + h;
            const float val = acc[s][r] + bias;
            if (mat == 0) {
                g_qb[((size_t)bh * NN + n) * HD + dd] = f2b(val * QS);
            } else if (mat == 1) {
                g_kb[((size_t)bh * NN + n) * HD + dd] = f2b(val);
            } else {
                g_tA[((size_t)bh * HD + dd) * NN + n] = f2b(val);
                g_acc[(size_t)rn * DD + j] = g_cf[h * 4] * val;
            }
        }
    }
}

// ---------------------------------------------------------------------------
// Kernel 2 (RESTRUCTURED, r9): attention pass, no LDS in the main loop.
// Block = 1 head x 32 queries; the 4 WAVES SPLIT THE KEYS (strips of 32,
// stride 128) -> no __syncthreads until the final combine.  K/T fragments
// load straight from global (kf coalesced 1KB/instr; tf 64B segments, L2).
// S^T trick: QK = mfma(A=K-rows, B=Q-rows) -> S^T[k][q] C-layout; after
// exp2, the PV B-frag (k=lg*8+j, n=ln) is rebuilt IN-REGISTER via 8
// __shfl + 4 selects (pack p-pairs first).  PV = mfma(A=T^T, B=P) ->
// O^T[d][q].  Plain-sum softmax: wave partials (O, lsum) add linearly;
// one 17 KB LDS reduction at the end combines the 4 waves.
// ---------------------------------------------------------------------------
__global__ __launch_bounds__(256) void attn_pass_kernel(const int kidx, const int dir)
{
    __shared__ float osh[4][32][33];   // [wave][q][d] (+1 pad)
    __shared__ float lsh[4][32];

    const unsigned short* __restrict__ tin  = dir ? g_tB : g_tA;
    unsigned short*       __restrict__ tout = dir ? g_tA : g_tB;

    const int tid = threadIdx.x;
    const int w   = tid >> 6;
    const int l   = tid & 63;
    const int lg  = l >> 4;
    const int ln  = l & 15;

    const int bh = blockIdx.x >> 6;    // b*H + h   (grid 32*64)
    const int qt = blockIdx.x & 63;
    const int h  = bh & (HH - 1);
    const int b  = bh >> 3;
    const int q0 = qt * 32;

    // Q B-frags: queries q0 + qi*16 + ln, dims lg*8.. (pre-scaled)
    short8 qf[2];
    #pragma unroll
    for (int qi = 0; qi < 2; ++qi)
        qf[qi] = *(const short8*)(g_qb +
            ((size_t)bh * NN + q0 + qi * 16 + ln) * HD + lg * 8);

    const unsigned short* kb = g_kb + (size_t)bh * NN * HD;
    const unsigned short* tb = tin  + (size_t)bh * HD * NN;

    f32x4 oacc[2][2] = {{{0,0,0,0},{0,0,0,0}},{{0,0,0,0},{0,0,0,0}}};
    float lsum[2] = {0.f, 0.f};
    const f32x4 zero = {0.f, 0.f, 0.f, 0.f};

    for (int it = 0; it < 16; ++it) {
        const int k0 = it * 128 + w * 32;   // this wave's 32-key strip
        // K rows as A-frags (m=key): coalesced 16B/lane
        const short8 kf0 = *(const short8*)(kb + (size_t)(k0 + ln) * HD + lg * 8);
        const short8 kf1 = *(const short8*)(kb + (size_t)(k0 + 16 + ln) * HD + lg * 8);
        // T^T rows as A-frags (m=dim): 64B segments
        const short8 tf0 = *(const short8*)(tb + (size_t)ln * NN + k0 + lg * 8);
        const short8 tf1 = *(const short8*)(tb + (size_t)(ln + 16) * NN + k0 + lg * 8);

        #pragma unroll
        for (int qi = 0; qi < 2; ++qi) {
            // S^T[k][q]: row=key-local lg*4+r, col=query ln
            f32x4 s0 = __builtin_amdgcn_mfma_f32_16x16x32_bf16(kf0, qf[qi], zero, 0, 0, 0);
            f32x4 s1 = __builtin_amdgcn_mfma_f32_16x16x32_bf16(kf1, qf[qi], zero, 0, 0, 0);

            float p[8];
            #pragma unroll
            for (int r = 0; r < 4; ++r) {
                p[r]     = exp2f(s0[r]);
                p[4 + r] = exp2f(s1[r]);
                lsum[qi] += p[r] + p[4 + r];
            }
            // pack pairs: pk[0]=keys(lg*4+0,1) pk[1]=(+2,3) of s0-set;
            //             pk[2],pk[3] same for s1-set (keys 16+..)
            unsigned int pk0 = pack2(p[0], p[1]);
            unsigned int pk1 = pack2(p[2], p[3]);
            unsigned int pk2 = pack2(p[4], p[5]);
            unsigned int pk3 = pack2(p[6], p[7]);

            // rebuild B-frag (k=lg*8+j*2{,+1}, n=ln) via shuffle transpose
            int bi[4];
            #pragma unroll
            for (int j = 0; j < 4; ++j) {
                const int srcLane = (((2 * lg + (j >> 1)) & 3) << 4) + ln;
                const int lo = __shfl((j & 1) ? (int)pk1 : (int)pk0, srcLane, 64);
                const int hi = __shfl((j & 1) ? (int)pk3 : (int)pk2, srcLane, 64);
                bi[j] = (lg < 2) ? lo : hi;
            }
            union { int i[4]; short8 s; } pf;
            pf.i[0] = bi[0]; pf.i[1] = bi[1]; pf.i[2] = bi[2]; pf.i[3] = bi[3];

            // O^T[d][q] += T^T P
            oacc[qi][0] = __builtin_amdgcn_mfma_f32_16x16x32_bf16(tf0, pf.s, oacc[qi][0], 0, 0, 0);
            oacc[qi][1] = __builtin_amdgcn_mfma_f32_16x16x32_bf16(tf1, pf.s, oacc[qi][1], 0, 0, 0);
        }
    }

    // in-wave lsum reduce across lg groups (lanes sharing ln): masks 16,32
    #pragma unroll
    for (int qi = 0; qi < 2; ++qi) {
        lsum[qi] += __shfl_xor(lsum[qi], 16, 64);
        lsum[qi] += __shfl_xor(lsum[qi], 32, 64);
    }
    if (lg == 0) { lsh[w][ln] = lsum[0]; lsh[w][16 + ln] = lsum[1]; }

    // store O^T wave-partials: row d = half*16+lg*4+r, col q = qi*16+ln
    #pragma unroll
    for (int qi = 0; qi < 2; ++qi)
        #pragma unroll
        for (int hf = 0; hf < 2; ++hf)
            #pragma unroll
            for (int r = 0; r < 4; ++r)
                osh[w][qi * 16 + ln][hf * 16 + lg * 4 + r] = oacc[qi][hf][r];
    __syncthreads();

    // combine 4 wave-partials; thread t: q = t&31, dims (t>>5)*4 ..+3
    {
        const int q  = tid & 31;
        const int db = (tid >> 5) * 4;
        const float invl = 1.0f / (lsh[0][q] + lsh[1][q] + lsh[2][q] + lsh[3][q]);
        const float ck = g_cf[h * 4 + kidx];
        #pragma unroll
        for (int dd = 0; dd < 4; ++dd) {
            const int d = db + dd;
            const float val = (osh[0][q][d] + osh[1][q][d] +
                               osh[2][q][d] + osh[3][q][d]) * invl;
            tout[((size_t)bh * HD + d) * NN + q0 + q] = f2b(val);
            float* ga = g_acc + ((size_t)(b * NN + q0 + q)) * DD + h * HD + d;
            *ga += ck * val;
        }
    }
}

// ---------------------------------------------------------------------------
// Kernel 3: output projection GEMM (unchanged).
// ---------------------------------------------------------------------------
__global__ __launch_bounds__(256) void out_gemm_kernel(void* __restrict__ out)
{
    __shared__ unsigned short xs[64 * 32];
    __shared__ unsigned short wl[64 * 32];
    const int f32m = g_isf32;
    const int t  = threadIdx.x;
    const int w  = t >> 6, l = t & 63, lg = l >> 4, ln = l & 15;
    const int r0 = blockIdx.x * 64;
    const int n0 = blockIdx.y * 64;
    const unsigned short* wt = g_wt + 3 * DD * DD;
    const int sr = t >> 2, sc = (t & 3) * 8;

    f32x4 acc[4] = {{0,0,0,0},{0,0,0,0},{0,0,0,0},{0,0,0,0}};

    for (int kc = 0; kc < DD; kc += 32) {
        __syncthreads();
        {
            const float* src = g_acc + (size_t)(r0 + sr) * DD + kc + sc;
            const float4 a = *(const float4*)src;
            const float4 b = *(const float4*)(src + 4);
            union { uint4 v; unsigned short s[8]; } o;
            o.s[0]=f2b(a.x); o.s[1]=f2b(a.y); o.s[2]=f2b(a.z); o.s[3]=f2b(a.w);
            o.s[4]=f2b(b.x); o.s[5]=f2b(b.y); o.s[6]=f2b(b.z); o.s[7]=f2b(b.w);
            *(uint4*)(xs + sr * 32 + sc) = o.v;
        }
        *(uint4*)(wl + sr * 32 + sc) =
            *(const uint4*)(wt + (size_t)(n0 + sr) * DD + kc + sc);
        __syncthreads();
        const short8 af = *(const short8*)(xs + (w * 16 + ln) * 32 + lg * 8);
        #pragma unroll
        for (int s = 0; s < 4; ++s) {
            const short8 bfr = *(const short8*)(wl + (s * 16 + ln) * 32 + lg * 8);
            acc[s] = __builtin_amdgcn_mfma_f32_16x16x32_bf16(af, bfr, acc[s], 0, 0, 0);
        }
    }

    #pragma unroll
    for (int s = 0; s < 4; ++s) {
        const int j = n0 + s * 16 + ln;
        const float bias = g_bias[3 * DD + j];
        #pragma unroll
        for (int r = 0; r < 4; ++r) {
            const int rn = r0 + w * 16 + lg * 4 + r;
            const float val = acc[s][r] + bias;
            if (f32m) ((float*)out)[(size_t)rn * DD + j] = val;
            else      ((bf16*)out)[(size_t)rn * DD + j] = __float2bfloat16(val);
        }
    }
}

// ---------------------------------------------------------------------------
extern "C" void kernel_launch(void* const* d_in, const int* in_sizes, int n_in,
                              void* d_out, int out_size, void* d_ws, size_t ws_size,
                              hipStream_t stream)
{
    const void* x      = d_in[0];
    const void* Wq     = d_in[1];
    const void* bq     = d_in[2];
    const void* Wk     = d_in[3];
    const void* bk     = d_in[4];
    const void* Wv     = d_in[5];
    const void* bv     = d_in[6];
    const void* Wo     = d_in[7];
    const void* bo     = d_in[8];
    const void* coeffs = d_in[9];
    (void)d_ws; (void)ws_size; (void)in_sizes; (void)n_in; (void)out_size;

    probe_kernel<<<1, 256, 0, stream>>>(x);

    prep_x_kernel<<<ELEMS / (256 * 8), 256, 0, stream>>>(x);
    prep_w_kernel<<<dim3(16, 4), 256, 0, stream>>>(Wq, Wk, Wv, Wo,
                                                   bq, bk, bv, bo, coeffs);

    qkv_gemm_kernel<<<dim3(128, 4, 3), 256, 0, stream>>>();

    const int agrid = (BB * HH) * (NN / 32);   // 32 * 64 = 2048 blocks
    attn_pass_kernel<<<agrid, 256, 0, stream>>>(1, 0); // tA -> tB
    attn_pass_kernel<<<agrid, 256, 0, stream>>>(2, 1); // tB -> tA
    attn_pass_kernel<<<agrid, 256, 0, stream>>>(3, 0); // tA -> tB

    out_gemm_kernel<<<dim3(128, 4), 256, 0, stream>>>(d_out);
}

// Round 10
// 260.081 us; speedup vs baseline: 1.2465x; 1.0648x over previous
//
#include <hip/hip_runtime.h>
#include <hip/hip_bf16.h>

typedef __hip_bfloat16 bf16;
typedef __attribute__((ext_vector_type(8))) short short8;   // 8 bf16 = 4 VGPRs
typedef __attribute__((ext_vector_type(4))) float f32x4;    // MFMA C/D

#define BB 4
#define NN 2048
#define DD 256
#define HH 8
#define HD 32
#define BN (BB*NN)          // 8192
#define ELEMS (BN*DD)       // 2097152

// ---------------------------------------------------------------------------
// Scratch in module .bss (~25 MB).
// ---------------------------------------------------------------------------
__device__ int g_isf32;
__device__ __attribute__((aligned(256))) unsigned short g_qb [ELEMS]; // [bh][n][d] bf16 (pre-scaled)
__device__ __attribute__((aligned(256))) unsigned short g_kb [ELEMS]; // [bh][n][d] bf16
__device__ __attribute__((aligned(256))) unsigned short g_tA [ELEMS]; // [bh][d][n] bf16
__device__ __attribute__((aligned(256))) unsigned short g_tB [ELEMS]; // [bh][d][n] bf16
__device__ __attribute__((aligned(256))) float          g_acc[ELEMS]; // [b][n][D] f32
__device__ __attribute__((aligned(256))) unsigned short g_wt [4*DD*DD]; // W^T bf16 [mat][n][k]
__device__ __attribute__((aligned(256))) float g_bias[4*DD];
__device__ __attribute__((aligned(256))) float g_cf[HH*4];

__device__ __forceinline__ float b2f(unsigned short u) {
    union { unsigned int i; float f; } c; c.i = ((unsigned int)u) << 16; return c.f;
}
__device__ __forceinline__ unsigned short f2b(float f) {           // safe path
    bf16 h = __float2bfloat16(f);
    return *reinterpret_cast<unsigned short*>(&h);
}
// fast RNE bf16-pair pack — valid for finite inputs (post-exp2, positive)
__device__ __forceinline__ unsigned int pack2f(float a, float b) {
    unsigned int ua = __float_as_uint(a), ub = __float_as_uint(b);
    ua = (ua + 0x7FFFu + ((ua >> 16) & 1u)) >> 16;
    ub = (ub + 0x7FFFu + ((ub >> 16) & 1u)) & 0xFFFF0000u;
    return ua | ub;
}
__device__ __forceinline__ float ldin(const void* p, int i, int f32m) {
    return f32m ? ((const float*)p)[i] : b2f(((const unsigned short*)p)[i]);
}

// ---------------------------------------------------------------------------
// Kernel 0: dtype probe (unchanged — verified rounds 4-9).
// ---------------------------------------------------------------------------
__global__ __launch_bounds__(256) void probe_kernel(const void* __restrict__ x)
{
    __shared__ int cnt;
    if (threadIdx.x == 0) cnt = 0;
    __syncthreads();
    const unsigned short* u = (const unsigned short*)x;
    int w = 0;
    for (int i = threadIdx.x; i < 1024; i += 256) {
        const int e = (u[2 * i] >> 7) & 0xFF;
        if (e < 100 || e > 140) ++w;
    }
    atomicAdd(&cnt, w);
    __syncthreads();
    if (threadIdx.x == 0) g_isf32 = (cnt > 300) ? 1 : 0;
}

// ---------------------------------------------------------------------------
// Prep: transpose W[k][n] -> g_wt[mat][n][k] bf16; block(0,0) also preps
// biases + coeffs to f32.
// ---------------------------------------------------------------------------
__global__ __launch_bounds__(256) void prep_w_kernel(
    const void* W0, const void* W1, const void* W2, const void* W3,
    const void* bq, const void* bk, const void* bv, const void* bo,
    const void* coeffs)
{
    const int f32m = g_isf32;
    __shared__ unsigned short tile[64][65];
    const int mat = blockIdx.y;
    const void* W = (mat == 0) ? W0 : (mat == 1) ? W1 : (mat == 2) ? W2 : W3;
    const int k0 = (blockIdx.x >> 2) * 64;
    const int n0 = (blockIdx.x & 3) * 64;
    const int t  = threadIdx.x;

    if (blockIdx.x == 0 && blockIdx.y == 0) {
        g_bias[0 * DD + t] = ldin(bq, t, f32m);
        g_bias[1 * DD + t] = ldin(bk, t, f32m);
        g_bias[2 * DD + t] = ldin(bv, t, f32m);
        g_bias[3 * DD + t] = ldin(bo, t, f32m);
        if (t < 32) g_cf[t] = ldin(coeffs, t, f32m);
    }

    #pragma unroll
    for (int it = 0; it < 16; ++it) {
        const int flat = it * 256 + t;
        const int i = flat >> 6, j = flat & 63;
        tile[j][i] = f2b(ldin(W, (k0 + i) * DD + n0 + j, f32m));
    }
    __syncthreads();
    unsigned short* wt = g_wt + mat * DD * DD;
    #pragma unroll
    for (int it = 0; it < 16; ++it) {
        const int flat = it * 256 + t;
        const int nl = flat >> 6, kl = flat & 63;
        wt[(n0 + nl) * DD + k0 + kl] = tile[nl][kl];
    }
}

// ---------------------------------------------------------------------------
// Kernel 1: QKV projection GEMM.  x read DIRECTLY from input (dual-dtype in
// the staging step — prep_x kernel removed).  q PRE-SCALED by scale*log2(e).
// ---------------------------------------------------------------------------
__global__ __launch_bounds__(256) void qkv_gemm_kernel(const void* __restrict__ x)
{
    __shared__ unsigned short xs[64 * 32];
    __shared__ unsigned short wl[64 * 32];
    const int f32m = g_isf32;
    const int t  = threadIdx.x;
    const int w  = t >> 6, l = t & 63, lg = l >> 4, ln = l & 15;
    const int r0 = blockIdx.x * 64;
    const int n0 = blockIdx.y * 64;
    const int mat = blockIdx.z;
    const unsigned short* wt = g_wt + mat * DD * DD;
    const int sr = t >> 2, sc = (t & 3) * 8;

    f32x4 acc[4] = {{0,0,0,0},{0,0,0,0},{0,0,0,0},{0,0,0,0}};

    for (int kc = 0; kc < DD; kc += 32) {
        __syncthreads();
        if (f32m) {
            const float* src = (const float*)x + (size_t)(r0 + sr) * DD + kc + sc;
            const float4 a = *(const float4*)src;
            const float4 b = *(const float4*)(src + 4);
            union { uint4 v; unsigned short s[8]; } o;
            o.s[0]=f2b(a.x); o.s[1]=f2b(a.y); o.s[2]=f2b(a.z); o.s[3]=f2b(a.w);
            o.s[4]=f2b(b.x); o.s[5]=f2b(b.y); o.s[6]=f2b(b.z); o.s[7]=f2b(b.w);
            *(uint4*)(xs + sr * 32 + sc) = o.v;
        } else {
            *(uint4*)(xs + sr * 32 + sc) =
                *(const uint4*)((const unsigned short*)x + (size_t)(r0 + sr) * DD + kc + sc);
        }
        *(uint4*)(wl + sr * 32 + sc) =
            *(const uint4*)(wt + (size_t)(n0 + sr) * DD + kc + sc);
        __syncthreads();
        const short8 af = *(const short8*)(xs + (w * 16 + ln) * 32 + lg * 8);
        #pragma unroll
        for (int s = 0; s < 4; ++s) {
            const short8 bfr = *(const short8*)(wl + (s * 16 + ln) * 32 + lg * 8);
            acc[s] = __builtin_amdgcn_mfma_f32_16x16x32_bf16(af, bfr, acc[s], 0, 0, 0);
        }
    }

    const float QS = 0.17677669529663687f * 1.4426950408889634f; // scale*log2e
    #pragma unroll
    for (int s = 0; s < 4; ++s) {
        const int j = n0 + s * 16 + ln;
        const float bias = g_bias[mat * DD + j];
        const int h = j >> 5, dd = j & 31;
        #pragma unroll
        for (int r = 0; r < 4; ++r) {
            const int rn = r0 + w * 16 + lg * 4 + r;
            const int b = rn >> 11, n = rn & (NN - 1);
            const int bh = b * HH + h;
            const float val = acc[s][r] + bias;
            if (mat == 0) {
                g_qb[((size_t)bh * NN + n) * HD + dd] = f2b(val * QS);
            } else if (mat == 1) {
                g_kb[((size_t)bh * NN + n) * HD + dd] = f2b(val);
            } else {
                g_tA[((size_t)bh * HD + dd) * NN + n] = f2b(val);
                g_acc[(size_t)rn * DD + j] = g_cf[h * 4] * val;
            }
        }
    }
}

// ---------------------------------------------------------------------------
// Kernel 2: attention pass (r9 structure — verified; r10 trims VALU only).
// Block = 1 head x 32 queries; 4 waves split keys (strips of 32, stride 128),
// no LDS in main loop.  S^T = mfma(K, Q) C-layout; exp2 via raw v_exp_f32
// (__builtin_amdgcn_exp2f — inputs finite); P B-frag rebuilt in-register via
// fast RNE pack (pack2f, no NaN path) + 8 __shfl + 4 selects; PV = mfma(T^T,
// P) -> O^T.  Plain-sum softmax; 17 KB end-of-kernel LDS combine of 4 waves.
// ---------------------------------------------------------------------------
__global__ __launch_bounds__(256) void attn_pass_kernel(const int kidx, const int dir)
{
    __shared__ float osh[4][32][33];   // [wave][q][d] (+1 pad)
    __shared__ float lsh[4][32];

    const unsigned short* __restrict__ tin  = dir ? g_tB : g_tA;
    unsigned short*       __restrict__ tout = dir ? g_tA : g_tB;

    const int tid = threadIdx.x;
    const int w   = tid >> 6;
    const int l   = tid & 63;
    const int lg  = l >> 4;
    const int ln  = l & 15;

    const int bh = blockIdx.x >> 6;    // b*H + h   (grid 32*64)
    const int qt = blockIdx.x & 63;
    const int h  = bh & (HH - 1);
    const int b  = bh >> 3;
    const int q0 = qt * 32;

    short8 qf[2];
    #pragma unroll
    for (int qi = 0; qi < 2; ++qi)
        qf[qi] = *(const short8*)(g_qb +
            ((size_t)bh * NN + q0 + qi * 16 + ln) * HD + lg * 8);

    const unsigned short* kb = g_kb + (size_t)bh * NN * HD;
    const unsigned short* tb = tin  + (size_t)bh * HD * NN;

    f32x4 oacc[2][2] = {{{0,0,0,0},{0,0,0,0}},{{0,0,0,0},{0,0,0,0}}};
    float lsum[2] = {0.f, 0.f};
    const f32x4 zero = {0.f, 0.f, 0.f, 0.f};

    for (int it = 0; it < 16; ++it) {
        const int k0 = it * 128 + w * 32;   // this wave's 32-key strip
        const short8 kf0 = *(const short8*)(kb + (size_t)(k0 + ln) * HD + lg * 8);
        const short8 kf1 = *(const short8*)(kb + (size_t)(k0 + 16 + ln) * HD + lg * 8);
        const short8 tf0 = *(const short8*)(tb + (size_t)ln * NN + k0 + lg * 8);
        const short8 tf1 = *(const short8*)(tb + (size_t)(ln + 16) * NN + k0 + lg * 8);

        #pragma unroll
        for (int qi = 0; qi < 2; ++qi) {
            f32x4 s0 = __builtin_amdgcn_mfma_f32_16x16x32_bf16(kf0, qf[qi], zero, 0, 0, 0);
            f32x4 s1 = __builtin_amdgcn_mfma_f32_16x16x32_bf16(kf1, qf[qi], zero, 0, 0, 0);

            float p[8];
            #pragma unroll
            for (int r = 0; r < 4; ++r) {
                p[r]     = __builtin_amdgcn_exp2f(s0[r]);
                p[4 + r] = __builtin_amdgcn_exp2f(s1[r]);
                lsum[qi] += p[r] + p[4 + r];
            }
            const unsigned int pk0 = pack2f(p[0], p[1]);
            const unsigned int pk1 = pack2f(p[2], p[3]);
            const unsigned int pk2 = pack2f(p[4], p[5]);
            const unsigned int pk3 = pack2f(p[6], p[7]);

            // rebuild B-frag (k=lg*8+j*2{,+1}, n=ln) via shuffle transpose
            int bi[4];
            #pragma unroll
            for (int j = 0; j < 4; ++j) {
                const int srcLane = (((2 * lg + (j >> 1)) & 3) << 4) + ln;
                const int lo = __shfl((j & 1) ? (int)pk1 : (int)pk0, srcLane, 64);
                const int hi = __shfl((j & 1) ? (int)pk3 : (int)pk2, srcLane, 64);
                bi[j] = (lg < 2) ? lo : hi;
            }
            union { int i[4]; short8 s; } pf;
            pf.i[0] = bi[0]; pf.i[1] = bi[1]; pf.i[2] = bi[2]; pf.i[3] = bi[3];

            oacc[qi][0] = __builtin_amdgcn_mfma_f32_16x16x32_bf16(tf0, pf.s, oacc[qi][0], 0, 0, 0);
            oacc[qi][1] = __builtin_amdgcn_mfma_f32_16x16x32_bf16(tf1, pf.s, oacc[qi][1], 0, 0, 0);
        }
    }

    #pragma unroll
    for (int qi = 0; qi < 2; ++qi) {
        lsum[qi] += __shfl_xor(lsum[qi], 16, 64);
        lsum[qi] += __shfl_xor(lsum[qi], 32, 64);
    }
    if (lg == 0) { lsh[w][ln] = lsum[0]; lsh[w][16 + ln] = lsum[1]; }

    #pragma unroll
    for (int qi = 0; qi < 2; ++qi)
        #pragma unroll
        for (int hf = 0; hf < 2; ++hf)
            #pragma unroll
            for (int r = 0; r < 4; ++r)
                osh[w][qi * 16 + ln][hf * 16 + lg * 4 + r] = oacc[qi][hf][r];
    __syncthreads();

    {
        const int q  = tid & 31;
        const int db = (tid >> 5) * 4;
        const float invl = 1.0f / (lsh[0][q] + lsh[1][q] + lsh[2][q] + lsh[3][q]);
        const float ck = g_cf[h * 4 + kidx];
        #pragma unroll
        for (int dd = 0; dd < 4; ++dd) {
            const int d = db + dd;
            const float val = (osh[0][q][d] + osh[1][q][d] +
                               osh[2][q][d] + osh[3][q][d]) * invl;
            tout[((size_t)bh * HD + d) * NN + q0 + q] = f2b(val);
            float* ga = g_acc + ((size_t)(b * NN + q0 + q)) * DD + h * HD + d;
            *ga += ck * val;
        }
    }
}

// ---------------------------------------------------------------------------
// Kernel 3: output projection GEMM (unchanged).
// ---------------------------------------------------------------------------
__global__ __launch_bounds__(256) void out_gemm_kernel(void* __restrict__ out)
{
    __shared__ unsigned short xs[64 * 32];
    __shared__ unsigned short wl[64 * 32];
    const int f32m = g_isf32;
    const int t  = threadIdx.x;
    const int w  = t >> 6, l = t & 63, lg = l >> 4, ln = l & 15;
    const int r0 = blockIdx.x * 64;
    const int n0 = blockIdx.y * 64;
    const unsigned short* wt = g_wt + 3 * DD * DD;
    const int sr = t >> 2, sc = (t & 3) * 8;

    f32x4 acc[4] = {{0,0,0,0},{0,0,0,0},{0,0,0,0},{0,0,0,0}};

    for (int kc = 0; kc < DD; kc += 32) {
        __syncthreads();
        {
            const float* src = g_acc + (size_t)(r0 + sr) * DD + kc + sc;
            const float4 a = *(const float4*)src;
            const float4 b = *(const float4*)(src + 4);
            union { uint4 v; unsigned short s[8]; } o;
            o.s[0]=f2b(a.x); o.s[1]=f2b(a.y); o.s[2]=f2b(a.z); o.s[3]=f2b(a.w);
            o.s[4]=f2b(b.x); o.s[5]=f2b(b.y); o.s[6]=f2b(b.z); o.s[7]=f2b(b.w);
            *(uint4*)(xs + sr * 32 + sc) = o.v;
        }
        *(uint4*)(wl + sr * 32 + sc) =
            *(const uint4*)(wt + (size_t)(n0 + sr) * DD + kc + sc);
        __syncthreads();
        const short8 af = *(const short8*)(xs + (w * 16 + ln) * 32 + lg * 8);
        #pragma unroll
        for (int s = 0; s < 4; ++s) {
            const short8 bfr = *(const short8*)(wl + (s * 16 + ln) * 32 + lg * 8);
            acc[s] = __builtin_amdgcn_mfma_f32_16x16x32_bf16(af, bfr, acc[s], 0, 0, 0);
        }
    }

    #pragma unroll
    for (int s = 0; s < 4; ++s) {
        const int j = n0 + s * 16 + ln;
        const float bias = g_bias[3 * DD + j];
        #pragma unroll
        for (int r = 0; r < 4; ++r) {
            const int rn = r0 + w * 16 + lg * 4 + r;
            const float val = acc[s][r] + bias;
            if (f32m) ((float*)out)[(size_t)rn * DD + j] = val;
            else      ((bf16*)out)[(size_t)rn * DD + j] = __float2bfloat16(val);
        }
    }
}

// ---------------------------------------------------------------------------
extern "C" void kernel_launch(void* const* d_in, const int* in_sizes, int n_in,
                              void* d_out, int out_size, void* d_ws, size_t ws_size,
                              hipStream_t stream)
{
    const void* x      = d_in[0];
    const void* Wq     = d_in[1];
    const void* bq     = d_in[2];
    const void* Wk     = d_in[3];
    const void* bk     = d_in[4];
    const void* Wv     = d_in[5];
    const void* bv     = d_in[6];
    const void* Wo     = d_in[7];
    const void* bo     = d_in[8];
    const void* coeffs = d_in[9];
    (void)d_ws; (void)ws_size; (void)in_sizes; (void)n_in; (void)out_size;

    probe_kernel<<<1, 256, 0, stream>>>(x);

    prep_w_kernel<<<dim3(16, 4), 256, 0, stream>>>(Wq, Wk, Wv, Wo,
                                                   bq, bk, bv, bo, coeffs);

    qkv_gemm_kernel<<<dim3(128, 4, 3), 256, 0, stream>>>(x);

    const int agrid = (BB * HH) * (NN / 32);   // 32 * 64 = 2048 blocks
    attn_pass_kernel<<<agrid, 256, 0, stream>>>(1, 0); // tA -> tB
    attn_pass_kernel<<<agrid, 256, 0, stream>>>(2, 1); // tB -> tA
    attn_pass_kernel<<<agrid, 256, 0, stream>>>(3, 0); // tA -> tB

    out_gemm_kernel<<<dim3(128, 4), 256, 0, stream>>>(d_out);
}

// Round 11
// 240.397 us; speedup vs baseline: 1.3486x; 1.0819x over previous
//
#include <hip/hip_runtime.h>
#include <hip/hip_bf16.h>

typedef __hip_bfloat16 bf16;
typedef __attribute__((ext_vector_type(8))) short short8;   // 8 bf16 = 4 VGPRs
typedef __attribute__((ext_vector_type(4))) short short4v;  // 4 bf16 = 2 VGPRs
typedef __attribute__((ext_vector_type(4))) float f32x4;    // MFMA C/D

#define BB 4
#define NN 2048
#define DD 256
#define HH 8
#define HD 32
#define BN (BB*NN)          // 8192
#define ELEMS (BN*DD)       // 2097152

// ---------------------------------------------------------------------------
// Scratch in module .bss (~25 MB).
// ---------------------------------------------------------------------------
__device__ int g_isf32;
__device__ __attribute__((aligned(256))) unsigned short g_qb [ELEMS]; // [bh][n][d] bf16 (pre-scaled)
__device__ __attribute__((aligned(256))) unsigned short g_kb [ELEMS]; // [bh][n][d] bf16
__device__ __attribute__((aligned(256))) unsigned short g_tA [ELEMS]; // [bh][d][n] bf16
__device__ __attribute__((aligned(256))) unsigned short g_tB [ELEMS]; // [bh][d][n] bf16
__device__ __attribute__((aligned(256))) float          g_acc[ELEMS]; // [b][n][D] f32
__device__ __attribute__((aligned(256))) unsigned short g_wt [4*DD*DD]; // W^T bf16 [mat][n][k]
__device__ __attribute__((aligned(256))) float g_bias[4*DD];
__device__ __attribute__((aligned(256))) float g_cf[HH*4];

__device__ __forceinline__ float b2f(unsigned short u) {
    union { unsigned int i; float f; } c; c.i = ((unsigned int)u) << 16; return c.f;
}
__device__ __forceinline__ unsigned short f2b(float f) {           // safe path
    bf16 h = __float2bfloat16(f);
    return *reinterpret_cast<unsigned short*>(&h);
}
// pack two f32 -> one u32 of two bf16 (RNE).  gfx950 has a 1-instr pk cvt.
#if __has_builtin(__builtin_amdgcn_cvt_pk_bf16_f32)
typedef __attribute__((ext_vector_type(2))) __bf16 bf16x2t;
__device__ __forceinline__ unsigned int pk2(float a, float b) {
    union { bf16x2t v; unsigned int u; } c;
    c.v = __builtin_amdgcn_cvt_pk_bf16_f32(a, b);
    return c.u;
}
#else
__device__ __forceinline__ unsigned int pk2(float a, float b) {
    unsigned int ua = __float_as_uint(a), ub = __float_as_uint(b);
    ua = (ua + 0x7FFFu + ((ua >> 16) & 1u)) >> 16;
    ub = (ub + 0x7FFFu + ((ub >> 16) & 1u)) & 0xFFFF0000u;
    return ua | ub;
}
#endif
__device__ __forceinline__ float ldin(const void* p, int i, int f32m) {
    return f32m ? ((const float*)p)[i] : b2f(((const unsigned short*)p)[i]);
}

// ---------------------------------------------------------------------------
// Kernel 0: dtype probe (unchanged — verified rounds 4-10).
// ---------------------------------------------------------------------------
__global__ __launch_bounds__(256) void probe_kernel(const void* __restrict__ x)
{
    __shared__ int cnt;
    if (threadIdx.x == 0) cnt = 0;
    __syncthreads();
    const unsigned short* u = (const unsigned short*)x;
    int w = 0;
    for (int i = threadIdx.x; i < 1024; i += 256) {
        const int e = (u[2 * i] >> 7) & 0xFF;
        if (e < 100 || e > 140) ++w;
    }
    atomicAdd(&cnt, w);
    __syncthreads();
    if (threadIdx.x == 0) g_isf32 = (cnt > 300) ? 1 : 0;
}

// ---------------------------------------------------------------------------
// Prep: transpose W[k][n] -> g_wt[mat][n][k] bf16; block(0,0) also preps
// biases + coeffs to f32.
// ---------------------------------------------------------------------------
__global__ __launch_bounds__(256) void prep_w_kernel(
    const void* W0, const void* W1, const void* W2, const void* W3,
    const void* bq, const void* bk, const void* bv, const void* bo,
    const void* coeffs)
{
    const int f32m = g_isf32;
    __shared__ unsigned short tile[64][65];
    const int mat = blockIdx.y;
    const void* W = (mat == 0) ? W0 : (mat == 1) ? W1 : (mat == 2) ? W2 : W3;
    const int k0 = (blockIdx.x >> 2) * 64;
    const int n0 = (blockIdx.x & 3) * 64;
    const int t  = threadIdx.x;

    if (blockIdx.x == 0 && blockIdx.y == 0) {
        g_bias[0 * DD + t] = ldin(bq, t, f32m);
        g_bias[1 * DD + t] = ldin(bk, t, f32m);
        g_bias[2 * DD + t] = ldin(bv, t, f32m);
        g_bias[3 * DD + t] = ldin(bo, t, f32m);
        if (t < 32) g_cf[t] = ldin(coeffs, t, f32m);
    }

    #pragma unroll
    for (int it = 0; it < 16; ++it) {
        const int flat = it * 256 + t;
        const int i = flat >> 6, j = flat & 63;
        tile[j][i] = f2b(ldin(W, (k0 + i) * DD + n0 + j, f32m));
    }
    __syncthreads();
    unsigned short* wt = g_wt + mat * DD * DD;
    #pragma unroll
    for (int it = 0; it < 16; ++it) {
        const int flat = it * 256 + t;
        const int nl = flat >> 6, kl = flat & 63;
        wt[(n0 + nl) * DD + k0 + kl] = tile[nl][kl];
    }
}

// ---------------------------------------------------------------------------
// Kernel 1: QKV projection GEMM (unchanged from r10).
// ---------------------------------------------------------------------------
__global__ __launch_bounds__(256) void qkv_gemm_kernel(const void* __restrict__ x)
{
    __shared__ unsigned short xs[64 * 32];
    __shared__ unsigned short wl[64 * 32];
    const int f32m = g_isf32;
    const int t  = threadIdx.x;
    const int w  = t >> 6, l = t & 63, lg = l >> 4, ln = l & 15;
    const int r0 = blockIdx.x * 64;
    const int n0 = blockIdx.y * 64;
    const int mat = blockIdx.z;
    const unsigned short* wt = g_wt + mat * DD * DD;
    const int sr = t >> 2, sc = (t & 3) * 8;

    f32x4 acc[4] = {{0,0,0,0},{0,0,0,0},{0,0,0,0},{0,0,0,0}};

    for (int kc = 0; kc < DD; kc += 32) {
        __syncthreads();
        if (f32m) {
            const float* src = (const float*)x + (size_t)(r0 + sr) * DD + kc + sc;
            const float4 a = *(const float4*)src;
            const float4 b = *(const float4*)(src + 4);
            union { uint4 v; unsigned short s[8]; } o;
            o.s[0]=f2b(a.x); o.s[1]=f2b(a.y); o.s[2]=f2b(a.z); o.s[3]=f2b(a.w);
            o.s[4]=f2b(b.x); o.s[5]=f2b(b.y); o.s[6]=f2b(b.z); o.s[7]=f2b(b.w);
            *(uint4*)(xs + sr * 32 + sc) = o.v;
        } else {
            *(uint4*)(xs + sr * 32 + sc) =
                *(const uint4*)((const unsigned short*)x + (size_t)(r0 + sr) * DD + kc + sc);
        }
        *(uint4*)(wl + sr * 32 + sc) =
            *(const uint4*)(wt + (size_t)(n0 + sr) * DD + kc + sc);
        __syncthreads();
        const short8 af = *(const short8*)(xs + (w * 16 + ln) * 32 + lg * 8);
        #pragma unroll
        for (int s = 0; s < 4; ++s) {
            const short8 bfr = *(const short8*)(wl + (s * 16 + ln) * 32 + lg * 8);
            acc[s] = __builtin_amdgcn_mfma_f32_16x16x32_bf16(af, bfr, acc[s], 0, 0, 0);
        }
    }

    const float QS = 0.17677669529663687f * 1.4426950408889634f; // scale*log2e
    #pragma unroll
    for (int s = 0; s < 4; ++s) {
        const int j = n0 + s * 16 + ln;
        const float bias = g_bias[mat * DD + j];
        const int h = j >> 5, dd = j & 31;
        #pragma unroll
        for (int r = 0; r < 4; ++r) {
            const int rn = r0 + w * 16 + lg * 4 + r;
            const int b = rn >> 11, n = rn & (NN - 1);
            const int bh = b * HH + h;
            const float val = acc[s][r] + bias;
            if (mat == 0) {
                g_qb[((size_t)bh * NN + n) * HD + dd] = f2b(val * QS);
            } else if (mat == 1) {
                g_kb[((size_t)bh * NN + n) * HD + dd] = f2b(val);
            } else {
                g_tA[((size_t)bh * HD + dd) * NN + n] = f2b(val);
                g_acc[(size_t)rn * DD + j] = g_cf[h * 4] * val;
            }
        }
    }
}

// ---------------------------------------------------------------------------
// Kernel 2 (r11): attention pass — shuffle-free PV via K=16 MFMA.
// Block = 1 head x 64 queries (4 Q-frags); 4 waves split keys (strips of 32).
// S^T = mfma_16x16x32(K, Q): C-layout [k=lg*4+r][q=ln].  That IS the
// B-operand layout of mfma_f32_16x16x16bf16_1k (B[k=lg*4+j][n=ln]), so after
// exp2 + 1-instr pk-cvt the P registers feed PV DIRECTLY — no shuffles, no
// selects (r10 spent 12 ops + 4.4M ds-permute conflict cycles there).
// PV A-operand = T^T[d=ln][k=lg*4+j], an 8B contiguous load.
// Plain-sum softmax; 35 KB end-of-kernel LDS combine of the 4 wave-partials.
// ---------------------------------------------------------------------------
__global__ __launch_bounds__(256) void attn_pass_kernel(const int kidx, const int dir)
{
    __shared__ float osh[4][64][33];   // [wave][q][d] (+1 pad)
    __shared__ float lsh[4][64];

    const unsigned short* __restrict__ tin  = dir ? g_tB : g_tA;
    unsigned short*       __restrict__ tout = dir ? g_tA : g_tB;

    const int tid = threadIdx.x;
    const int w   = tid >> 6;
    const int l   = tid & 63;
    const int lg  = l >> 4;
    const int ln  = l & 15;

    const int bh = blockIdx.x >> 5;    // b*H + h   (grid 32*32)
    const int qt = blockIdx.x & 31;
    const int h  = bh & (HH - 1);
    const int b  = bh >> 3;
    const int q0 = qt * 64;

    short8 qf[4];
    #pragma unroll
    for (int qi = 0; qi < 4; ++qi)
        qf[qi] = *(const short8*)(g_qb +
            ((size_t)bh * NN + q0 + qi * 16 + ln) * HD + lg * 8);

    const unsigned short* kb = g_kb + (size_t)bh * NN * HD;
    const unsigned short* tb = tin  + (size_t)bh * HD * NN;

    f32x4 oacc[4][2];
    #pragma unroll
    for (int qi = 0; qi < 4; ++qi) { oacc[qi][0] = (f32x4){0,0,0,0}; oacc[qi][1] = (f32x4){0,0,0,0}; }
    float lsum[4] = {0.f, 0.f, 0.f, 0.f};
    const f32x4 zero = {0.f, 0.f, 0.f, 0.f};

    for (int it = 0; it < 16; ++it) {
        const int k0 = it * 128 + w * 32;   // this wave's 32-key strip
        const short8 kf0 = *(const short8*)(kb + (size_t)(k0 + ln) * HD + lg * 8);
        const short8 kf1 = *(const short8*)(kb + (size_t)(k0 + 16 + ln) * HD + lg * 8);

#if __has_builtin(__builtin_amdgcn_mfma_f32_16x16x16bf16_1k)
        // T^T A-frags for K=16 PV: [c=key-chunk][hf=dim-half], 8B each
        short4v tf[2][2];
        #pragma unroll
        for (int c = 0; c < 2; ++c)
            #pragma unroll
            for (int hf = 0; hf < 2; ++hf)
                tf[c][hf] = *(const short4v*)(tb +
                    (size_t)(hf * 16 + ln) * NN + k0 + c * 16 + lg * 4);

        #pragma unroll
        for (int qi = 0; qi < 4; ++qi) {
            f32x4 s0 = __builtin_amdgcn_mfma_f32_16x16x32_bf16(kf0, qf[qi], zero, 0, 0, 0);
            f32x4 s1 = __builtin_amdgcn_mfma_f32_16x16x32_bf16(kf1, qf[qi], zero, 0, 0, 0);
            float p[8];
            #pragma unroll
            for (int r = 0; r < 4; ++r) {
                p[r]     = __builtin_amdgcn_exp2f(s0[r]);
                p[4 + r] = __builtin_amdgcn_exp2f(s1[r]);
                lsum[qi] += p[r] + p[4 + r];
            }
            union { unsigned int u[2]; short4v s; } pb0, pb1;
            pb0.u[0] = pk2(p[0], p[1]); pb0.u[1] = pk2(p[2], p[3]);
            pb1.u[0] = pk2(p[4], p[5]); pb1.u[1] = pk2(p[6], p[7]);
            oacc[qi][0] = __builtin_amdgcn_mfma_f32_16x16x16bf16_1k(tf[0][0], pb0.s, oacc[qi][0], 0, 0, 0);
            oacc[qi][1] = __builtin_amdgcn_mfma_f32_16x16x16bf16_1k(tf[0][1], pb0.s, oacc[qi][1], 0, 0, 0);
            oacc[qi][0] = __builtin_amdgcn_mfma_f32_16x16x16bf16_1k(tf[1][0], pb1.s, oacc[qi][0], 0, 0, 0);
            oacc[qi][1] = __builtin_amdgcn_mfma_f32_16x16x16bf16_1k(tf[1][1], pb1.s, oacc[qi][1], 0, 0, 0);
        }
#else
        // fallback: r10's verified shuffle-transpose path (K=32 PV)
        const short8 tf0 = *(const short8*)(tb + (size_t)ln * NN + k0 + lg * 8);
        const short8 tf1 = *(const short8*)(tb + (size_t)(ln + 16) * NN + k0 + lg * 8);
        #pragma unroll
        for (int qi = 0; qi < 4; ++qi) {
            f32x4 s0 = __builtin_amdgcn_mfma_f32_16x16x32_bf16(kf0, qf[qi], zero, 0, 0, 0);
            f32x4 s1 = __builtin_amdgcn_mfma_f32_16x16x32_bf16(kf1, qf[qi], zero, 0, 0, 0);
            float p[8];
            #pragma unroll
            for (int r = 0; r < 4; ++r) {
                p[r]     = __builtin_amdgcn_exp2f(s0[r]);
                p[4 + r] = __builtin_amdgcn_exp2f(s1[r]);
                lsum[qi] += p[r] + p[4 + r];
            }
            const unsigned int pk0 = pk2(p[0], p[1]);
            const unsigned int pk1 = pk2(p[2], p[3]);
            const unsigned int pk2v = pk2(p[4], p[5]);
            const unsigned int pk3 = pk2(p[6], p[7]);
            int bi[4];
            #pragma unroll
            for (int j = 0; j < 4; ++j) {
                const int srcLane = (((2 * lg + (j >> 1)) & 3) << 4) + ln;
                const int lo = __shfl((j & 1) ? (int)pk1 : (int)pk0, srcLane, 64);
                const int hi = __shfl((j & 1) ? (int)pk3 : (int)pk2v, srcLane, 64);
                bi[j] = (lg < 2) ? lo : hi;
            }
            union { int i[4]; short8 s; } pf;
            pf.i[0] = bi[0]; pf.i[1] = bi[1]; pf.i[2] = bi[2]; pf.i[3] = bi[3];
            oacc[qi][0] = __builtin_amdgcn_mfma_f32_16x16x32_bf16(tf0, pf.s, oacc[qi][0], 0, 0, 0);
            oacc[qi][1] = __builtin_amdgcn_mfma_f32_16x16x32_bf16(tf1, pf.s, oacc[qi][1], 0, 0, 0);
        }
#endif
    }

    // lsum: reduce across lg groups (lanes sharing ln)
    #pragma unroll
    for (int qi = 0; qi < 4; ++qi) {
        lsum[qi] += __shfl_xor(lsum[qi], 16, 64);
        lsum[qi] += __shfl_xor(lsum[qi], 32, 64);
    }
    if (lg == 0) {
        #pragma unroll
        for (int qi = 0; qi < 4; ++qi) lsh[w][qi * 16 + ln] = lsum[qi];
    }

    // store O^T wave-partials: row q = qi*16+ln, col d = hf*16+lg*4+r
    #pragma unroll
    for (int qi = 0; qi < 4; ++qi)
        #pragma unroll
        for (int hf = 0; hf < 2; ++hf)
            #pragma unroll
            for (int r = 0; r < 4; ++r)
                osh[w][qi * 16 + ln][hf * 16 + lg * 4 + r] = oacc[qi][hf][r];
    __syncthreads();

    // combine 4 wave-partials; thread t: q = t&63, dims (t>>6)*8 ..+7
    {
        const int q  = tid & 63;
        const int db = (tid >> 6) * 8;
        const float invl = 1.0f / (lsh[0][q] + lsh[1][q] + lsh[2][q] + lsh[3][q]);
        const float ck = g_cf[h * 4 + kidx];
        #pragma unroll
        for (int dd = 0; dd < 8; ++dd) {
            const int d = db + dd;
            const float val = (osh[0][q][d] + osh[1][q][d] +
                               osh[2][q][d] + osh[3][q][d]) * invl;
            tout[((size_t)bh * HD + d) * NN + q0 + q] = f2b(val);
            float* ga = g_acc + ((size_t)(b * NN + q0 + q)) * DD + h * HD + d;
            *ga += ck * val;
        }
    }
}

// ---------------------------------------------------------------------------
// Kernel 3: output projection GEMM (unchanged).
// ---------------------------------------------------------------------------
__global__ __launch_bounds__(256) void out_gemm_kernel(void* __restrict__ out)
{
    __shared__ unsigned short xs[64 * 32];
    __shared__ unsigned short wl[64 * 32];
    const int f32m = g_isf32;
    const int t  = threadIdx.x;
    const int w  = t >> 6, l = t & 63, lg = l >> 4, ln = l & 15;
    const int r0 = blockIdx.x * 64;
    const int n0 = blockIdx.y * 64;
    const unsigned short* wt = g_wt + 3 * DD * DD;
    const int sr = t >> 2, sc = (t & 3) * 8;

    f32x4 acc[4] = {{0,0,0,0},{0,0,0,0},{0,0,0,0},{0,0,0,0}};

    for (int kc = 0; kc < DD; kc += 32) {
        __syncthreads();
        {
            const float* src = g_acc + (size_t)(r0 + sr) * DD + kc + sc;
            const float4 a = *(const float4*)src;
            const float4 b = *(const float4*)(src + 4);
            union { uint4 v; unsigned short s[8]; } o;
            o.s[0]=f2b(a.x); o.s[1]=f2b(a.y); o.s[2]=f2b(a.z); o.s[3]=f2b(a.w);
            o.s[4]=f2b(b.x); o.s[5]=f2b(b.y); o.s[6]=f2b(b.z); o.s[7]=f2b(b.w);
            *(uint4*)(xs + sr * 32 + sc) = o.v;
        }
        *(uint4*)(wl + sr * 32 + sc) =
            *(const uint4*)(wt + (size_t)(n0 + sr) * DD + kc + sc);
        __syncthreads();
        const short8 af = *(const short8*)(xs + (w * 16 + ln) * 32 + lg * 8);
        #pragma unroll
        for (int s = 0; s < 4; ++s) {
            const short8 bfr = *(const short8*)(wl + (s * 16 + ln) * 32 + lg * 8);
            acc[s] = __builtin_amdgcn_mfma_f32_16x16x32_bf16(af, bfr, acc[s], 0, 0, 0);
        }
    }

    #pragma unroll
    for (int s = 0; s < 4; ++s) {
        const int j = n0 + s * 16 + ln;
        const float bias = g_bias[3 * DD + j];
        #pragma unroll
        for (int r = 0; r < 4; ++r) {
            const int rn = r0 + w * 16 + lg * 4 + r;
            const float val = acc[s][r] + bias;
            if (f32m) ((float*)out)[(size_t)rn * DD + j] = val;
            else      ((bf16*)out)[(size_t)rn * DD + j] = __float2bfloat16(val);
        }
    }
}

// ---------------------------------------------------------------------------
extern "C" void kernel_launch(void* const* d_in, const int* in_sizes, int n_in,
                              void* d_out, int out_size, void* d_ws, size_t ws_size,
                              hipStream_t stream)
{
    const void* x      = d_in[0];
    const void* Wq     = d_in[1];
    const void* bq     = d_in[2];
    const void* Wk     = d_in[3];
    const void* bk     = d_in[4];
    const void* Wv     = d_in[5];
    const void* bv     = d_in[6];
    const void* Wo     = d_in[7];
    const void* bo     = d_in[8];
    const void* coeffs = d_in[9];
    (void)d_ws; (void)ws_size; (void)in_sizes; (void)n_in; (void)out_size;

    probe_kernel<<<1, 256, 0, stream>>>(x);

    prep_w_kernel<<<dim3(16, 4), 256, 0, stream>>>(Wq, Wk, Wv, Wo,
                                                   bq, bk, bv, bo, coeffs);

    qkv_gemm_kernel<<<dim3(128, 4, 3), 256, 0, stream>>>(x);

    const int agrid = (BB * HH) * (NN / 64);   // 32 * 32 = 1024 blocks
    attn_pass_kernel<<<agrid, 256, 0, stream>>>(1, 0); // tA -> tB
    attn_pass_kernel<<<agrid, 256, 0, stream>>>(2, 1); // tB -> tA
    attn_pass_kernel<<<agrid, 256, 0, stream>>>(3, 0); // tA -> tB

    out_gemm_kernel<<<dim3(128, 4), 256, 0, stream>>>(d_out);
}